// Round 13
// baseline (127.537 us; speedup 1.0000x reference)
//
#include <hip/hip_runtime.h>
#include <hip/hip_bf16.h>

#define NN 8192
#define INF 128
#define OUTF 64
#define EMB 32
#define LOG2E 1.4426950408889634f
#define ISPLIT 64
#define ICH (NN / ISPLIT)
#define MGUARD 64.0f
#define JS 8
#define JCH (NN / JS)

typedef __attribute__((ext_vector_type(8))) short bf16x8;
typedef __attribute__((ext_vector_type(4))) float f32x4;

// workspace offsets (bytes)
#define OFF_HB   0u          // bf16 hB[4][256][64][8] fragment-ready : 1048576
#define OFF_UW   1048576u    // float2 UW[8192] = (2^u, 2^w)          : 65536
#define OFF_E12  1114112u    // float2 e12[8192] = (e1,e2)*log2e      : 65536
#define OFF_S    1179648u    // f32 S[8192] column sums (atomic)      : 32768
#define OFF_CNT  1212416u    // int cnt[64] per-M-tile arrivals       : 256
#define OFF_PART 1212928u    // f32 part[JS][8192][64]

// hB element (nb,tile,l,e) = h[tile*32 + (l>>4)*8 + e][nb*16 + (l&15)]
// -> k4 B-fragment load for a wave = contiguous 1KB (64 lanes x 16B).

// ---- Kernel 1: h = input@W (16 rows/block) -> hB, UW, e12; zero S, cnt ----
__global__ __launch_bounds__(256) void k1_h(
    const float* __restrict__ input, const float* __restrict__ Wm,
    const float* __restrict__ av, const float* __restrict__ embeds,
    const float* __restrict__ intw, const float* __restrict__ betap,
    ushort* __restrict__ hB, float2* __restrict__ UW,
    float2* __restrict__ e12, float* __restrict__ S, int* __restrict__ cnt)
{
    __shared__ float hl[16][65];
    const int t    = threadIdx.x;
    const int wid  = t >> 6;
    const int lane = t & 63;
    const int blk  = blockIdx.x;
    const int i0 = blk * 16 + wid * 4;

    if (t < 16) S[blk * 16 + t] = 0.f;      // zero atomic accumulator each call
    if (blk == 0 && t < 64) cnt[t] = 0;     // zero tile arrival counters

    const float a1 = av[lane];
    const float a2 = av[64 + lane];
    const float* x0 = input + (size_t)i0 * INF;

    float acc0 = 0.f, acc1 = 0.f, acc2 = 0.f, acc3 = 0.f;
#pragma unroll 4
    for (int k = 0; k < INF; k += 4) {
        const float wk0 = Wm[(k + 0) * OUTF + lane];
        const float wk1 = Wm[(k + 1) * OUTF + lane];
        const float wk2 = Wm[(k + 2) * OUTF + lane];
        const float wk3 = Wm[(k + 3) * OUTF + lane];
        const float4 xa = *(const float4*)(x0 + k);
        const float4 xb = *(const float4*)(x0 + INF + k);
        const float4 xc = *(const float4*)(x0 + 2 * INF + k);
        const float4 xd = *(const float4*)(x0 + 3 * INF + k);
        acc0 = fmaf(xa.x, wk0, acc0); acc0 = fmaf(xa.y, wk1, acc0);
        acc0 = fmaf(xa.z, wk2, acc0); acc0 = fmaf(xa.w, wk3, acc0);
        acc1 = fmaf(xb.x, wk0, acc1); acc1 = fmaf(xb.y, wk1, acc1);
        acc1 = fmaf(xb.z, wk2, acc1); acc1 = fmaf(xb.w, wk3, acc1);
        acc2 = fmaf(xc.x, wk0, acc2); acc2 = fmaf(xc.y, wk1, acc2);
        acc2 = fmaf(xc.z, wk2, acc2); acc2 = fmaf(xc.w, wk3, acc2);
        acc3 = fmaf(xd.x, wk0, acc3); acc3 = fmaf(xd.y, wk1, acc3);
        acc3 = fmaf(xd.z, wk2, acc3); acc3 = fmaf(xd.w, wk3, acc3);
    }

    hl[wid * 4 + 0][lane] = acc0;
    hl[wid * 4 + 1][lane] = acc1;
    hl[wid * 4 + 2][lane] = acc2;
    hl[wid * 4 + 3][lane] = acc3;

    float accs[4] = {acc0, acc1, acc2, acc3};
#pragma unroll
    for (int r = 0; r < 4; ++r) {
        float v1 = accs[r] * a1;
        float v2 = accs[r] * a2;
#pragma unroll
        for (int o = 32; o > 0; o >>= 1) {
            v1 += __shfl_xor(v1, o);
            v2 += __shfl_xor(v2, o);
        }
        float p = 0.f;
        if (lane < EMB) p = embeds[(size_t)(i0 + r) * EMB + lane] * intw[lane];
#pragma unroll
        for (int o = 16; o > 0; o >>= 1) p += __shfl_xor(p, o);

        if (lane == 0) {
            const float q = betap[0] * p;
            UW[i0 + r] = make_float2(
                __builtin_amdgcn_exp2f((v1 + q) * LOG2E),
                __builtin_amdgcn_exp2f((0.2f * v1 + q) * LOG2E));
            e12[i0 + r] = make_float2(v2 * LOG2E, 0.2f * v2 * LOG2E);
        }
    }

    __syncthreads();
    // fragment-ready store: 128 threads x 16B (layout HW-verified R5/R6)
    if (t < 128) {
        const int rr = t >> 6;
        const int of = t & 63;
        const int nb = of >> 4;
        const int r2 = of & 15;
        const int tile = blk >> 1;
        const int g = (blk & 1) * 2 + rr;
        const int l = g * 16 + r2;
        union { bf16x8 v; ushort us[8]; } pk;
#pragma unroll
        for (int e = 0; e < 8; ++e) {
            __hip_bfloat16 b = __float2bfloat16(hl[rr * 8 + e][of]);
            pk.us[e] = *(ushort*)&b;
        }
        *(bf16x8*)(hB + (size_t)(((nb * 256 + tile) * 64 + l) * 8)) = pk.v;
    }
}

// ---- Kernel 2: partial column sums -> atomic S[j] (exp-free) ----
__global__ __launch_bounds__(256) void k2_colsum(
    const float2* __restrict__ UW, const float2* __restrict__ e12,
    float* __restrict__ S)
{
    const int j0 = blockIdx.x * 256 + threadIdx.x;   // [0,4096)
    const int j1 = j0 + 4096;
    const float2 ea = e12[j0];
    const float2 eb = e12[j1];
    const float Ma = fmaxf(ea.x, ea.y) + MGUARD;
    const float Mb = fmaxf(eb.x, eb.y) + MGUARD;
    const float Pa = __builtin_amdgcn_exp2f(ea.x - Ma);
    const float Qa = __builtin_amdgcn_exp2f(ea.y - Ma);
    const float Pb = __builtin_amdgcn_exp2f(eb.x - Mb);
    const float Qb = __builtin_amdgcn_exp2f(eb.y - Mb);

    const float* up = (const float*)UW + (size_t)blockIdx.y * ICH * 2;
    float sa = 0.f, sb = 0.f;
#pragma unroll 8
    for (int rr = 0; rr < ICH * 2; rr += 4) {
        const float4 c = *(const float4*)(up + rr);   // U0 W0 U1 W1
        sa += fmaxf(c.x * Pa, c.y * Qa);
        sa += fmaxf(c.z * Pa, c.w * Qa);
        sb += fmaxf(c.x * Pb, c.y * Qb);
        sb += fmaxf(c.z * Pb, c.w * Qb);
    }
    unsafeAtomicAdd(&S[j0], sa);
    unsafeAtomicAdd(&S[j1], sb);
}

// ---- Kernel 4: attn @ h partials (R11 form) + tail-election combine/ELU ----
__global__ __launch_bounds__(256) void k4_mm(
    const float2* __restrict__ UW, const float2* __restrict__ e12,
    const float* __restrict__ S, const ushort* __restrict__ hB,
    float* __restrict__ part, int* __restrict__ cnt, float* __restrict__ out)
{
    __shared__ float2 pq[JCH];   // normalized (P/S, Q/S) for this j-chunk
    __shared__ int lastFlag;

    const int wid  = threadIdx.x >> 6;
    const int lane = threadIdx.x & 63;
    const int r = lane & 15;
    const int g = lane >> 4;
    const int mt = blockIdx.x;
    const int ibase = mt * 128 + wid * 32;
    const int jb = blockIdx.y * JCH;

    // prologue: per-chunk normalized factors (same M expr as k2 -> exact cancel)
    for (int c = threadIdx.x; c < JCH; c += 256) {
        const float2 e = e12[jb + c];
        const float M = fmaxf(e.x, e.y) + MGUARD;
        const float inv = 1.0f / S[jb + c];
        pq[c] = make_float2(__builtin_amdgcn_exp2f(e.x - M) * inv,
                            __builtin_amdgcn_exp2f(e.y - M) * inv);
    }
    __syncthreads();

    const float2 c0 = UW[ibase + r];
    const float2 c1 = UW[ibase + 16 + r];

    f32x4 a00 = {0,0,0,0}, a01 = {0,0,0,0}, a02 = {0,0,0,0}, a03 = {0,0,0,0};
    f32x4 a10 = {0,0,0,0}, a11 = {0,0,0,0}, a12 = {0,0,0,0}, a13 = {0,0,0,0};

    for (int j0 = jb; j0 < jb + JCH; j0 += 32) {
        const int jj = j0 + g * 8;
        const float* pqp = (const float*)&pq[jj - jb];
        const float4 q0 = *(const float4*)(pqp);       // P0 Q0 P1 Q1
        const float4 q1 = *(const float4*)(pqp + 4);
        const float4 q2 = *(const float4*)(pqp + 8);
        const float4 q3 = *(const float4*)(pqp + 12);

        float e00 = fmaxf(c0.x * q0.x, c0.y * q0.y);
        float e01 = fmaxf(c0.x * q0.z, c0.y * q0.w);
        float e02 = fmaxf(c0.x * q1.x, c0.y * q1.y);
        float e03 = fmaxf(c0.x * q1.z, c0.y * q1.w);
        float e04 = fmaxf(c0.x * q2.x, c0.y * q2.y);
        float e05 = fmaxf(c0.x * q2.z, c0.y * q2.w);
        float e06 = fmaxf(c0.x * q3.x, c0.y * q3.y);
        float e07 = fmaxf(c0.x * q3.z, c0.y * q3.w);

        float e10 = fmaxf(c1.x * q0.x, c1.y * q0.y);
        float e11 = fmaxf(c1.x * q0.z, c1.y * q0.w);
        float e12v= fmaxf(c1.x * q1.x, c1.y * q1.y);
        float e13 = fmaxf(c1.x * q1.z, c1.y * q1.w);
        float e14 = fmaxf(c1.x * q2.x, c1.y * q2.y);
        float e15 = fmaxf(c1.x * q2.z, c1.y * q2.w);
        float e16 = fmaxf(c1.x * q3.x, c1.y * q3.y);
        float e17 = fmaxf(c1.x * q3.z, c1.y * q3.w);

        union { bf16x8 v; unsigned u[4]; } A0, A1;
        asm("v_cvt_pk_bf16_f32 %0, %1, %2" : "=v"(A0.u[0]) : "v"(e00), "v"(e01));
        asm("v_cvt_pk_bf16_f32 %0, %1, %2" : "=v"(A0.u[1]) : "v"(e02), "v"(e03));
        asm("v_cvt_pk_bf16_f32 %0, %1, %2" : "=v"(A0.u[2]) : "v"(e04), "v"(e05));
        asm("v_cvt_pk_bf16_f32 %0, %1, %2" : "=v"(A0.u[3]) : "v"(e06), "v"(e07));
        asm("v_cvt_pk_bf16_f32 %0, %1, %2" : "=v"(A1.u[0]) : "v"(e10), "v"(e11));
        asm("v_cvt_pk_bf16_f32 %0, %1, %2" : "=v"(A1.u[1]) : "v"(e12v),"v"(e13));
        asm("v_cvt_pk_bf16_f32 %0, %1, %2" : "=v"(A1.u[2]) : "v"(e14), "v"(e15));
        asm("v_cvt_pk_bf16_f32 %0, %1, %2" : "=v"(A1.u[3]) : "v"(e16), "v"(e17));

        const int tile = j0 >> 5;
        const ushort* hb = hB + (size_t)(tile * 64 + lane) * 8;
        const bf16x8 b0 = *(const bf16x8*)(hb);
        const bf16x8 b1 = *(const bf16x8*)(hb + 256 * 64 * 8);
        const bf16x8 b2 = *(const bf16x8*)(hb + 2 * 256 * 64 * 8);
        const bf16x8 b3 = *(const bf16x8*)(hb + 3 * 256 * 64 * 8);

        a00 = __builtin_amdgcn_mfma_f32_16x16x32_bf16(A0.v, b0, a00, 0, 0, 0);
        a01 = __builtin_amdgcn_mfma_f32_16x16x32_bf16(A0.v, b1, a01, 0, 0, 0);
        a02 = __builtin_amdgcn_mfma_f32_16x16x32_bf16(A0.v, b2, a02, 0, 0, 0);
        a03 = __builtin_amdgcn_mfma_f32_16x16x32_bf16(A0.v, b3, a03, 0, 0, 0);
        a10 = __builtin_amdgcn_mfma_f32_16x16x32_bf16(A1.v, b0, a10, 0, 0, 0);
        a11 = __builtin_amdgcn_mfma_f32_16x16x32_bf16(A1.v, b1, a11, 0, 0, 0);
        a12 = __builtin_amdgcn_mfma_f32_16x16x32_bf16(A1.v, b2, a12, 0, 0, 0);
        a13 = __builtin_amdgcn_mfma_f32_16x16x32_bf16(A1.v, b3, a13, 0, 0, 0);
    }

    float* pout = part + (size_t)blockIdx.y * (NN * OUTF);
#pragma unroll
    for (int m = 0; m < 4; ++m) {
        const int row0 = ibase + g * 4 + m;
        const int row1 = ibase + 16 + g * 4 + m;
        pout[(size_t)row0 * OUTF + 0  + r] = a00[m];
        pout[(size_t)row0 * OUTF + 16 + r] = a01[m];
        pout[(size_t)row0 * OUTF + 32 + r] = a02[m];
        pout[(size_t)row0 * OUTF + 48 + r] = a03[m];
        pout[(size_t)row1 * OUTF + 0  + r] = a10[m];
        pout[(size_t)row1 * OUTF + 16 + r] = a11[m];
        pout[(size_t)row1 * OUTF + 32 + r] = a12[m];
        pout[(size_t)row1 * OUTF + 48 + r] = a13[m];
    }

    // tail election: 8th arriver for this M-tile combines + ELU (no spinning)
    __threadfence();
    __syncthreads();
    if (threadIdx.x == 0) {
        const int old = __hip_atomic_fetch_add(&cnt[mt], 1, __ATOMIC_ACQ_REL,
                                               __HIP_MEMORY_SCOPE_AGENT);
        lastFlag = (old == JS - 1);
    }
    __syncthreads();
    if (lastFlag) {
        const size_t tbase = (size_t)mt * 128 * OUTF;   // this tile's 8192 floats
        for (int k = threadIdx.x; k < 128 * OUTF; k += 256) {
            float v = 0.f;
#pragma unroll
            for (int s = 0; s < JS; ++s) {
                v += __hip_atomic_load(&part[(size_t)s * (NN * OUTF) + tbase + k],
                                       __ATOMIC_RELAXED, __HIP_MEMORY_SCOPE_AGENT);
            }
            out[tbase + k] =
                v > 0.f ? v : (__builtin_amdgcn_exp2f(v * LOG2E) - 1.f);
        }
    }
}

extern "C" void kernel_launch(void* const* d_in, const int* in_sizes, int n_in,
                              void* d_out, int out_size, void* d_ws, size_t ws_size,
                              hipStream_t stream)
{
    const float* input  = (const float*)d_in[0];
    // d_in[1] = adj : unused by the reference computation
    const float* embeds = (const float*)d_in[2];
    const float* Wm     = (const float*)d_in[3];
    const float* av     = (const float*)d_in[4];
    const float* intw   = (const float*)d_in[5];
    // d_in[6] = intent_b : cancels in column softmax
    const float* betap  = (const float*)d_in[7];
    float* out = (float*)d_out;

    char* ws = (char*)d_ws;
    ushort* hB  = (ushort*)(ws + OFF_HB);
    float2* UW  = (float2*)(ws + OFF_UW);
    float2* e12 = (float2*)(ws + OFF_E12);
    float* S    = (float*)(ws + OFF_S);
    int*   cnt  = (int*)(ws + OFF_CNT);
    float* part = (float*)(ws + OFF_PART);

    k1_h<<<NN / 16, 256, 0, stream>>>(input, Wm, av, embeds, intw, betap,
                                      hB, UW, e12, S, cnt);
    k2_colsum<<<dim3(NN / 512, ISPLIT), 256, 0, stream>>>(UW, e12, S);
    k4_mm<<<dim3(64, JS), 256, 0, stream>>>(UW, e12, S, hB, part, cnt, out);
}

// Round 14
// 56.841 us; speedup vs baseline: 2.2438x; 2.2438x over previous
//
#include <hip/hip_runtime.h>
#include <hip/hip_bf16.h>

#define NN 8192
#define INF 128
#define OUTF 64
#define EMB 32
#define LOG2E 1.4426950408889634f
#define ISPLIT 64
#define ICH (NN / ISPLIT)
#define MGUARD 64.0f

typedef __attribute__((ext_vector_type(8))) short bf16x8;
typedef __attribute__((ext_vector_type(4))) float f32x4;

// workspace offsets (bytes)
#define OFF_HB   0u          // bf16 hB[4][256][64][8] fragment-ready : 1048576
#define OFF_UW   1048576u    // float2 UW[8192] = (2^u, 2^w)          : 65536
#define OFF_E12  1114112u    // float2 e12[8192] = (e1,e2)*log2e      : 65536
#define OFF_S    1179648u    // f32 S[8192] column sums (atomic)      : 32768
#define OFF_PART 1212416u    // f32 part[JS][8192][64]

// hB element (nb,tile,l,e) = h[tile*32 + (l>>4)*8 + e][nb*16 + (l&15)]
// -> k4 B-fragment load for a wave = contiguous 1KB (64 lanes x 16B).

// ---- Kernel 1: h = input@W (16 rows/block) -> hB, UW, e12; zero S ----
__global__ __launch_bounds__(256) void k1_h(
    const float* __restrict__ input, const float* __restrict__ Wm,
    const float* __restrict__ av, const float* __restrict__ embeds,
    const float* __restrict__ intw, const float* __restrict__ betap,
    ushort* __restrict__ hB, float2* __restrict__ UW,
    float2* __restrict__ e12, float* __restrict__ S)
{
    __shared__ float hl[16][65];
    const int t    = threadIdx.x;
    const int wid  = t >> 6;
    const int lane = t & 63;
    const int blk  = blockIdx.x;
    const int i0 = blk * 16 + wid * 4;

    if (t < 16) S[blk * 16 + t] = 0.f;   // zero atomic accumulator each call

    const float a1 = av[lane];
    const float a2 = av[64 + lane];
    const float* x0 = input + (size_t)i0 * INF;

    float acc0 = 0.f, acc1 = 0.f, acc2 = 0.f, acc3 = 0.f;
#pragma unroll 4
    for (int k = 0; k < INF; k += 4) {
        const float wk0 = Wm[(k + 0) * OUTF + lane];
        const float wk1 = Wm[(k + 1) * OUTF + lane];
        const float wk2 = Wm[(k + 2) * OUTF + lane];
        const float wk3 = Wm[(k + 3) * OUTF + lane];
        const float4 xa = *(const float4*)(x0 + k);
        const float4 xb = *(const float4*)(x0 + INF + k);
        const float4 xc = *(const float4*)(x0 + 2 * INF + k);
        const float4 xd = *(const float4*)(x0 + 3 * INF + k);
        acc0 = fmaf(xa.x, wk0, acc0); acc0 = fmaf(xa.y, wk1, acc0);
        acc0 = fmaf(xa.z, wk2, acc0); acc0 = fmaf(xa.w, wk3, acc0);
        acc1 = fmaf(xb.x, wk0, acc1); acc1 = fmaf(xb.y, wk1, acc1);
        acc1 = fmaf(xb.z, wk2, acc1); acc1 = fmaf(xb.w, wk3, acc1);
        acc2 = fmaf(xc.x, wk0, acc2); acc2 = fmaf(xc.y, wk1, acc2);
        acc2 = fmaf(xc.z, wk2, acc2); acc2 = fmaf(xc.w, wk3, acc2);
        acc3 = fmaf(xd.x, wk0, acc3); acc3 = fmaf(xd.y, wk1, acc3);
        acc3 = fmaf(xd.z, wk2, acc3); acc3 = fmaf(xd.w, wk3, acc3);
    }

    hl[wid * 4 + 0][lane] = acc0;
    hl[wid * 4 + 1][lane] = acc1;
    hl[wid * 4 + 2][lane] = acc2;
    hl[wid * 4 + 3][lane] = acc3;

    float accs[4] = {acc0, acc1, acc2, acc3};
#pragma unroll
    for (int r = 0; r < 4; ++r) {
        float v1 = accs[r] * a1;
        float v2 = accs[r] * a2;
#pragma unroll
        for (int o = 32; o > 0; o >>= 1) {
            v1 += __shfl_xor(v1, o);
            v2 += __shfl_xor(v2, o);
        }
        float p = 0.f;
        if (lane < EMB) p = embeds[(size_t)(i0 + r) * EMB + lane] * intw[lane];
#pragma unroll
        for (int o = 16; o > 0; o >>= 1) p += __shfl_xor(p, o);

        if (lane == 0) {
            const float q = betap[0] * p;
            UW[i0 + r] = make_float2(
                __builtin_amdgcn_exp2f((v1 + q) * LOG2E),
                __builtin_amdgcn_exp2f((0.2f * v1 + q) * LOG2E));
            e12[i0 + r] = make_float2(v2 * LOG2E, 0.2f * v2 * LOG2E);
        }
    }

    __syncthreads();
    // fragment-ready store: 128 threads x 16B (layout HW-verified R5/R6)
    if (t < 128) {
        const int rr = t >> 6;
        const int of = t & 63;
        const int nb = of >> 4;
        const int r2 = of & 15;
        const int tile = blk >> 1;
        const int g = (blk & 1) * 2 + rr;
        const int l = g * 16 + r2;
        union { bf16x8 v; ushort us[8]; } pk;
#pragma unroll
        for (int e = 0; e < 8; ++e) {
            __hip_bfloat16 b = __float2bfloat16(hl[rr * 8 + e][of]);
            pk.us[e] = *(ushort*)&b;
        }
        *(bf16x8*)(hB + (size_t)(((nb * 256 + tile) * 64 + l) * 8)) = pk.v;
    }
}

// ---- Kernel 2: partial column sums -> atomic S[j] (exp-free) ----
__global__ __launch_bounds__(256) void k2_colsum(
    const float2* __restrict__ UW, const float2* __restrict__ e12,
    float* __restrict__ S)
{
    const int j0 = blockIdx.x * 256 + threadIdx.x;   // [0,4096)
    const int j1 = j0 + 4096;
    const float2 ea = e12[j0];
    const float2 eb = e12[j1];
    const float Ma = fmaxf(ea.x, ea.y) + MGUARD;
    const float Mb = fmaxf(eb.x, eb.y) + MGUARD;
    const float Pa = __builtin_amdgcn_exp2f(ea.x - Ma);
    const float Qa = __builtin_amdgcn_exp2f(ea.y - Ma);
    const float Pb = __builtin_amdgcn_exp2f(eb.x - Mb);
    const float Qb = __builtin_amdgcn_exp2f(eb.y - Mb);

    const float* up = (const float*)UW + (size_t)blockIdx.y * ICH * 2;
    float sa = 0.f, sb = 0.f;
#pragma unroll 8
    for (int rr = 0; rr < ICH * 2; rr += 4) {
        const float4 c = *(const float4*)(up + rr);   // U0 W0 U1 W1
        sa += fmaxf(c.x * Pa, c.y * Qa);
        sa += fmaxf(c.z * Pa, c.w * Qa);
        sb += fmaxf(c.x * Pb, c.y * Qb);
        sb += fmaxf(c.z * Pb, c.w * Qb);
    }
    unsafeAtomicAdd(&S[j0], sa);
    unsafeAtomicAdd(&S[j1], sb);
}

// ---- Kernel 4: h_prime partial = attention @ h (MFMA bf16, LDS pq prologue) ----
__global__ __launch_bounds__(256) void k4_mm(
    const float2* __restrict__ UW, const float2* __restrict__ e12,
    const float* __restrict__ S, const ushort* __restrict__ hB,
    float* __restrict__ part, int jch)
{
    __shared__ float2 pq[2048];   // normalized (P/S, Q/S) for this j-chunk

    const int wid  = threadIdx.x >> 6;
    const int lane = threadIdx.x & 63;
    const int r = lane & 15;
    const int g = lane >> 4;
    const int ibase = blockIdx.x * 128 + wid * 32;
    const int jb = blockIdx.y * jch;

    // prologue: per-chunk normalized factors (same M expr as k2 -> exact cancel)
    for (int c = threadIdx.x; c < jch; c += 256) {
        const float2 e = e12[jb + c];
        const float M = fmaxf(e.x, e.y) + MGUARD;
        const float inv = 1.0f / S[jb + c];
        pq[c] = make_float2(__builtin_amdgcn_exp2f(e.x - M) * inv,
                            __builtin_amdgcn_exp2f(e.y - M) * inv);
    }
    __syncthreads();

    const float2 c0 = UW[ibase + r];        // (U,W) for A-frag0 row
    const float2 c1 = UW[ibase + 16 + r];   // (U,W) for A-frag1 row

    f32x4 a00 = {0,0,0,0}, a01 = {0,0,0,0}, a02 = {0,0,0,0}, a03 = {0,0,0,0};
    f32x4 a10 = {0,0,0,0}, a11 = {0,0,0,0}, a12 = {0,0,0,0}, a13 = {0,0,0,0};

    for (int j0 = jb; j0 < jb + jch; j0 += 32) {
        const int jj = j0 + g * 8;
        const float* pqp = (const float*)&pq[jj - jb];
        const float4 q0 = *(const float4*)(pqp);       // P0 Q0 P1 Q1
        const float4 q1 = *(const float4*)(pqp + 4);
        const float4 q2 = *(const float4*)(pqp + 8);
        const float4 q3 = *(const float4*)(pqp + 12);

        float e00 = fmaxf(c0.x * q0.x, c0.y * q0.y);
        float e01 = fmaxf(c0.x * q0.z, c0.y * q0.w);
        float e02 = fmaxf(c0.x * q1.x, c0.y * q1.y);
        float e03 = fmaxf(c0.x * q1.z, c0.y * q1.w);
        float e04 = fmaxf(c0.x * q2.x, c0.y * q2.y);
        float e05 = fmaxf(c0.x * q2.z, c0.y * q2.w);
        float e06 = fmaxf(c0.x * q3.x, c0.y * q3.y);
        float e07 = fmaxf(c0.x * q3.z, c0.y * q3.w);

        float e10 = fmaxf(c1.x * q0.x, c1.y * q0.y);
        float e11 = fmaxf(c1.x * q0.z, c1.y * q0.w);
        float e12v= fmaxf(c1.x * q1.x, c1.y * q1.y);
        float e13 = fmaxf(c1.x * q1.z, c1.y * q1.w);
        float e14 = fmaxf(c1.x * q2.x, c1.y * q2.y);
        float e15 = fmaxf(c1.x * q2.z, c1.y * q2.w);
        float e16 = fmaxf(c1.x * q3.x, c1.y * q3.y);
        float e17 = fmaxf(c1.x * q3.z, c1.y * q3.w);

        union { bf16x8 v; unsigned u[4]; } A0, A1;
        asm("v_cvt_pk_bf16_f32 %0, %1, %2" : "=v"(A0.u[0]) : "v"(e00), "v"(e01));
        asm("v_cvt_pk_bf16_f32 %0, %1, %2" : "=v"(A0.u[1]) : "v"(e02), "v"(e03));
        asm("v_cvt_pk_bf16_f32 %0, %1, %2" : "=v"(A0.u[2]) : "v"(e04), "v"(e05));
        asm("v_cvt_pk_bf16_f32 %0, %1, %2" : "=v"(A0.u[3]) : "v"(e06), "v"(e07));
        asm("v_cvt_pk_bf16_f32 %0, %1, %2" : "=v"(A1.u[0]) : "v"(e10), "v"(e11));
        asm("v_cvt_pk_bf16_f32 %0, %1, %2" : "=v"(A1.u[1]) : "v"(e12v),"v"(e13));
        asm("v_cvt_pk_bf16_f32 %0, %1, %2" : "=v"(A1.u[2]) : "v"(e14), "v"(e15));
        asm("v_cvt_pk_bf16_f32 %0, %1, %2" : "=v"(A1.u[3]) : "v"(e16), "v"(e17));

        const int tile = j0 >> 5;
        const ushort* hb = hB + (size_t)(tile * 64 + lane) * 8;
        const bf16x8 b0 = *(const bf16x8*)(hb);
        const bf16x8 b1 = *(const bf16x8*)(hb + 256 * 64 * 8);
        const bf16x8 b2 = *(const bf16x8*)(hb + 2 * 256 * 64 * 8);
        const bf16x8 b3 = *(const bf16x8*)(hb + 3 * 256 * 64 * 8);

        a00 = __builtin_amdgcn_mfma_f32_16x16x32_bf16(A0.v, b0, a00, 0, 0, 0);
        a01 = __builtin_amdgcn_mfma_f32_16x16x32_bf16(A0.v, b1, a01, 0, 0, 0);
        a02 = __builtin_amdgcn_mfma_f32_16x16x32_bf16(A0.v, b2, a02, 0, 0, 0);
        a03 = __builtin_amdgcn_mfma_f32_16x16x32_bf16(A0.v, b3, a03, 0, 0, 0);
        a10 = __builtin_amdgcn_mfma_f32_16x16x32_bf16(A1.v, b0, a10, 0, 0, 0);
        a11 = __builtin_amdgcn_mfma_f32_16x16x32_bf16(A1.v, b1, a11, 0, 0, 0);
        a12 = __builtin_amdgcn_mfma_f32_16x16x32_bf16(A1.v, b2, a12, 0, 0, 0);
        a13 = __builtin_amdgcn_mfma_f32_16x16x32_bf16(A1.v, b3, a13, 0, 0, 0);
    }

    float* pout = part + (size_t)blockIdx.y * (NN * OUTF);
#pragma unroll
    for (int m = 0; m < 4; ++m) {
        const int row0 = ibase + g * 4 + m;
        const int row1 = ibase + 16 + g * 4 + m;
        pout[(size_t)row0 * OUTF + 0  + r] = a00[m];
        pout[(size_t)row0 * OUTF + 16 + r] = a01[m];
        pout[(size_t)row0 * OUTF + 32 + r] = a02[m];
        pout[(size_t)row0 * OUTF + 48 + r] = a03[m];
        pout[(size_t)row1 * OUTF + 0  + r] = a10[m];
        pout[(size_t)row1 * OUTF + 16 + r] = a11[m];
        pout[(size_t)row1 * OUTF + 32 + r] = a12[m];
        pout[(size_t)row1 * OUTF + 48 + r] = a13[m];
    }
}

// ---- Kernel 5: combine j-split partials + ELU (float4) ----
__global__ __launch_bounds__(256) void k5_combine(
    const float* __restrict__ part, float* __restrict__ out, int JS)
{
    const int base = (blockIdx.x * 256 + threadIdx.x) * 4;
    float4 v = make_float4(0.f, 0.f, 0.f, 0.f);
    for (int s = 0; s < JS; ++s) {
        const float4 p = *(const float4*)(part + (size_t)s * (NN * OUTF) + base);
        v.x += p.x; v.y += p.y; v.z += p.z; v.w += p.w;
    }
    float4 o;
    o.x = v.x > 0.f ? v.x : (__builtin_amdgcn_exp2f(v.x * LOG2E) - 1.f);
    o.y = v.y > 0.f ? v.y : (__builtin_amdgcn_exp2f(v.y * LOG2E) - 1.f);
    o.z = v.z > 0.f ? v.z : (__builtin_amdgcn_exp2f(v.z * LOG2E) - 1.f);
    o.w = v.w > 0.f ? v.w : (__builtin_amdgcn_exp2f(v.w * LOG2E) - 1.f);
    *(float4*)(out + base) = o;
}

extern "C" void kernel_launch(void* const* d_in, const int* in_sizes, int n_in,
                              void* d_out, int out_size, void* d_ws, size_t ws_size,
                              hipStream_t stream)
{
    const float* input  = (const float*)d_in[0];
    // d_in[1] = adj : unused by the reference computation
    const float* embeds = (const float*)d_in[2];
    const float* Wm     = (const float*)d_in[3];
    const float* av     = (const float*)d_in[4];
    const float* intw   = (const float*)d_in[5];
    // d_in[6] = intent_b : cancels in column softmax
    const float* betap  = (const float*)d_in[7];
    float* out = (float*)d_out;

    char* ws = (char*)d_ws;
    ushort* hB  = (ushort*)(ws + OFF_HB);
    float2* UW  = (float2*)(ws + OFF_UW);
    float2* e12 = (float2*)(ws + OFF_E12);
    float* S    = (float*)(ws + OFF_S);
    float* part = (float*)(ws + OFF_PART);

    int JS = 8;   // jch must be <= 2048 (LDS pq buffer)
    while (JS > 4 &&
           (size_t)OFF_PART + (size_t)JS * NN * OUTF * sizeof(float) > ws_size)
        JS >>= 1;
    const int jch = NN / JS;

    k1_h<<<NN / 16, 256, 0, stream>>>(input, Wm, av, embeds, intw, betap,
                                      hB, UW, e12, S);
    k2_colsum<<<dim3(NN / 512, ISPLIT), 256, 0, stream>>>(UW, e12, S);
    k4_mm<<<dim3(NN / 128, JS), 256, 0, stream>>>(UW, e12, S, hB, part, jch);
    k5_combine<<<(NN * OUTF) / 1024, 256, 0, stream>>>(part, out, JS);
}